// Round 9
// baseline (100.293 us; speedup 1.0000x reference)
//
#include <hip/hip_runtime.h>
#include <hip/hip_bf16.h>

// GraphProp: layered DAG topological propagation.
// N=50000, L=16 levels, PER=3125/level, DEG=16 in-edges, D=64 feat dim.
// Edges sorted by dst; node v (v>=PER) owns edges [(v-PER)*16, +16).
// feat[v] = max_k(feat[src_k] + intra[src_k]) + delay[v], level order.
//
// R9: chunked msgT + compressed barrier + cross-barrier prefetch.
//  - 8 feature chunks x 32 blocks (chunk c = blocks b&7==c -> XCD-local
//    under round-robin dispatch; perf-only assumption).
//  - msgT rows PADDED TO 64B (one L2 line == one node). This closes the
//    line-straddle race latent in R7/R8 (32B rows, PER odd -> a line held
//    two nodes from adjacent levels; cached gather of the old row could
//    capture its line-mate stale while the sc1 write was in flight).
//    With 64B rows a line is written entirely before any reader touches
//    it -> cached msgT reads are provably final. Replays are safe by
//    determinism (stale L2 lines hold identical values).
//  - barrier = direct count: arrive is one RMW per block on the chunk's
//    counter; spinners poll the count (no leader scan, no release word).
//    2 LLC round trips per level instead of ~4.
//  - overlap window: after arriving, issue out store + next-level
//    src/delay/intra + gathers of ALREADY-FINAL sources (s < l*PER);
//    these fly across a RAW s_barrier (no vmcnt drain -> loads live).
//    Post-barrier critical path: ~16/l fresh gathers + fmax + msgT store.
//  - exact reference arithmetic (out = max + delay), absmax must be 0.

#define NN    50000
#define LVL   16
#define PER   3125
#define DEG   16
#define DF    64

#define NBLK  256
#define NTHR  1024
#define NCH   8
#define BPC   32                    // blocks per chunk
#define ROWF  16                    // floats per padded msgT row (64B)

// ws layout (bytes)
#define OFF_CNT   0                 // unsigned cnt[8], 128B apart
#define OFF_MSGT  8192
#define MSGT_BYTES ((size_t)NN * NCH * ROWF * 4)    // 25.6 MB
#define WS_NEED   (OFF_MSGT + MSGT_BYTES)

__device__ __forceinline__ void st_sc1_f(float* p, float v) {
    __hip_atomic_store(p, v, __ATOMIC_RELAXED, __HIP_MEMORY_SCOPE_AGENT);
}
__device__ __forceinline__ unsigned ld_sc1_u(const unsigned* p) {
    return __hip_atomic_load(p, __ATOMIC_RELAXED, __HIP_MEMORY_SCOPE_AGENT);
}

#define UNPACK16(dst, a0, a1, a2, a3)                                   \
    dst[0]=a0.x; dst[1]=a0.y; dst[2]=a0.z; dst[3]=a0.w;                 \
    dst[4]=a1.x; dst[5]=a1.y; dst[6]=a1.z; dst[7]=a1.w;                 \
    dst[8]=a2.x; dst[9]=a2.y; dst[10]=a2.z; dst[11]=a2.w;               \
    dst[12]=a3.x; dst[13]=a3.y; dst[14]=a3.z; dst[15]=a3.w;

__global__ void __launch_bounds__(NTHR) prop_chunk3(
    const float* __restrict__ feat,
    const float* __restrict__ delay,
    const float* __restrict__ intra,
    const int*  __restrict__ src,
    float* __restrict__ out,
    char*  __restrict__ ws)
{
    float* msgT = (float*)(ws + OFF_MSGT);
    const int b    = blockIdx.x;
    const int c    = b & 7;                      // chunk (== XCD, perf only)
    const int rank = b >> 3;                     // 0..31 within chunk
    unsigned* cnt  = (unsigned*)(ws + OFF_CNT) + c * 32;   // 128B apart
    const int cbase = c * NN;

    // ---- init: chunk c's blocks build chunk c's level-0 msgT ----
    {
        const int i = rank * NTHR + threadIdx.x;         // [0, 32768)
        if (i < PER * 8) {
            const int v = i >> 3, jj = i & 7;
            const int dd = c * 8 + jj;
            st_sc1_f(&msgT[(size_t)(cbase + v) * ROWF + jj],
                     feat[(size_t)v * DF + dd] + intra[(size_t)v * DF + dd]);
        }
    }

    const int lane = threadIdx.x & 63;
    const int w    = threadIdx.x >> 6;
    const int n    = lane >> 3, j = lane & 7;    // 8 nodes x 8 feats / wave
    const int nv   = (rank * 16 + w) * 8 + n;    // node-within-level
    const bool act = (nv < PER);
    const int d    = c * 8 + j;                  // global feature index

    float g[DEG];
#pragma unroll
    for (int k = 0; k < DEG; ++k) g[k] = -INFINITY;
    int   sidx[DEG];
    float dl = 0.f, it = 0.f;

    // Level-1 metadata (read-only arrays; load any time).
    if (act) {
        const int4* sp = (const int4*)(src + (size_t)nv * DEG);
        int4 a0 = sp[0], a1 = sp[1], a2 = sp[2], a3 = sp[3];
        UNPACK16(sidx, a0, a1, a2, a3);
        dl = delay[(size_t)(PER + nv) * DF + d];
        it = intra[(size_t)(PER + nv) * DF + d];
    }

    // ---- init barrier (phase 1): drain msgT-0, count, poll ----
    asm volatile("s_waitcnt vmcnt(0)" ::: "memory");
    asm volatile("s_barrier" ::: "memory");
    if (threadIdx.x == 0) {
        __hip_atomic_fetch_add(cnt, 1u, __ATOMIC_RELAXED,
                               __HIP_MEMORY_SCOPE_AGENT);
        while (ld_sc1_u(cnt) < (unsigned)BPC) __builtin_amdgcn_s_sleep(1);
    }
    asm volatile("s_barrier" ::: "memory");

    // ---- level loop ----
    for (int l = 1; l < LVL; ++l) {
        const int v       = l * PER + nv;
        const int lim_old = (l - 1) * PER;       // < lim_old: gathered already
        float o = 0.f;
        if (act) {
            // fresh gathers: sources in level l-1 (visible since last barrier)
#pragma unroll
            for (int k = 0; k < DEG; ++k)
                if (sidx[k] >= lim_old)
                    g[k] = msgT[(size_t)(cbase + sidx[k]) * ROWF + j];
            float m = -INFINITY;
#pragma unroll
            for (int k = 0; k < DEG; ++k) m = fmaxf(m, g[k]);
            o = m + dl;
            if (l < LVL - 1)
                st_sc1_f(&msgT[(size_t)(cbase + v) * ROWF + j], o + it);
        }
        if (l == LVL - 1) {                      // last level: no sync needed
            if (act) st_sc1_f(&out[(size_t)v * DF + d], o);
            break;
        }

        // ---- arrive: drain msgT store, then one RMW per block ----
        asm volatile("s_waitcnt vmcnt(0)" ::: "memory");
        asm volatile("s_barrier" ::: "memory");
        if (threadIdx.x == 0)
            __hip_atomic_fetch_add(cnt, 1u, __ATOMIC_RELAXED,
                                   __HIP_MEMORY_SCOPE_AGENT);

        // ---- overlap window: work that needs no barrier ----
        if (act) {
            st_sc1_f(&out[(size_t)v * DF + d], o);       // flies past barrier
            const int vn = v + PER;                      // next level's node
            const int4* sp = (const int4*)(src + (size_t)(vn - PER) * DEG);
            int4 a0 = sp[0], a1 = sp[1], a2 = sp[2], a3 = sp[3];
            UNPACK16(sidx, a0, a1, a2, a3);
            dl = delay[(size_t)vn * DF + d];
            it = intra[(size_t)vn * DF + d];
            const int lim_new = l * PER;                 // < lim_new: final now
#pragma unroll
            for (int k = 0; k < DEG; ++k)
                g[k] = (sidx[k] < lim_new)
                     ? msgT[(size_t)(cbase + sidx[k]) * ROWF + j]
                     : -INFINITY;
        }

        // ---- release: poll count, raw s_barrier (prefetches stay live) ----
        if (threadIdx.x == 0) {
            const unsigned tgt = (unsigned)((l + 1) * BPC);
            while (ld_sc1_u(cnt) < tgt) __builtin_amdgcn_s_sleep(1);
        }
        asm volatile("s_barrier" ::: "memory");
    }
}

// ---- fallback path (ws too small): round-1 multi-kernel approach ----
__global__ void __launch_bounds__(256) prop_level(
    float* __restrict__ feat, const float* __restrict__ intra,
    const float* __restrict__ delay, const int* __restrict__ src, int level_start)
{
    const int idx = blockIdx.x * 4 + (threadIdx.x >> 6);
    if (idx >= PER) return;
    const int v = level_start + idx;
    const int d = threadIdx.x & 63;
    const long ebase = (long)(v - PER) * DEG;
    float m = -INFINITY;
#pragma unroll
    for (int k = 0; k < DEG; ++k) {
        const int s = src[ebase + k];
        m = fmaxf(m, feat[(long)s * DF + d] + intra[(long)s * DF + d]);
    }
    feat[(long)v * DF + d] = m + delay[(long)v * DF + d];
}

extern "C" void kernel_launch(void* const* d_in, const int* in_sizes, int n_in,
                              void* d_out, int out_size, void* d_ws, size_t ws_size,
                              hipStream_t stream) {
    const float* feat  = (const float*)d_in[0];
    const float* delay = (const float*)d_in[1];
    const float* intra = (const float*)d_in[2];
    const int*   src   = (const int*)d_in[3];
    float* out = (float*)d_out;

    if (ws_size >= WS_NEED) {
        hipMemsetAsync(d_ws, 0, 8192, stream);          // counters -> 0
        // level-0 rows of out = feat (contiguous 0.8 MB)
        hipMemcpyAsync(out, feat, (size_t)PER * DF * sizeof(float),
                       hipMemcpyDeviceToDevice, stream);
        prop_chunk3<<<NBLK, NTHR, 0, stream>>>(feat, delay, intra, src, out,
                                               (char*)d_ws);
    } else {
        hipMemcpyAsync(out, feat, (size_t)NN * DF * sizeof(float),
                       hipMemcpyDeviceToDevice, stream);
        const int blocks = (PER + 3) / 4;
        for (int l = 1; l < LVL; ++l)
            prop_level<<<blocks, 256, 0, stream>>>(out, intra, delay, src, l * PER);
    }
}